// Round 1
// baseline (1372.776 us; speedup 1.0000x reference)
//
#include <hip/hip_runtime.h>
#include <math.h>

#define HW_N 2304      // H*W tokens
#define CB   384       // input channels
#define HIDD 512       // hidden
#define DD   128       // feature dim
#define KK   64        // clusters
#define BATCH 32
#define M1   65        // KK + 1 (dust bin)
#define NORM_ARG 2368.0f  // m + n = 64 + 2304

// ---------------------------------------------------------------------------
// Batched GEMM: C[b][m][n] = act(sum_k A[m][k] * X[b][k][n] + bias[m])
// A row-major [M,K] shared across batch. 64x64 tile, BK=16, 4x4 per thread.
// ---------------------------------------------------------------------------
template<bool RELU>
__global__ __launch_bounds__(256)
void gemm_bias_act(const float* __restrict__ A,
                   const float* __restrict__ bias,
                   const float* __restrict__ X, long xBatchStride,
                   float* __restrict__ C, long cBatchStride,
                   int M, int Kdim, int N)
{
    const int BK = 16;
    __shared__ float As[16][68];  // [kk][m], +4 pad keeps 16B align, spreads banks
    __shared__ float Xs[16][68];  // [kk][n]

    const int bn = blockIdx.x, bm = blockIdx.y, b = blockIdx.z;
    const float* Xb = X + (long)b * xBatchStride;
    float* Cb = C + (long)b * cBatchStride;

    const int tid = threadIdx.x;
    const int tm = tid >> 4;      // 0..15
    const int tn = tid & 15;      // 0..15
    const int m0 = bm << 6, n0 = bn << 6;

    float acc[4][4] = {};

    for (int k0 = 0; k0 < Kdim; k0 += BK) {
        // A tile: 64 x 16 -> As[kk][m]
        #pragma unroll
        for (int i = 0; i < 4; i++) {
            int li = tid + (i << 8);
            int m = li >> 4, kk = li & 15;
            As[kk][m] = A[(long)(m0 + m) * Kdim + k0 + kk];
        }
        // X tile: 16 x 64 -> Xs[kk][n]
        #pragma unroll
        for (int i = 0; i < 4; i++) {
            int li = tid + (i << 8);
            int kk = li >> 6, n = li & 63;
            Xs[kk][n] = Xb[(long)(k0 + kk) * N + n0 + n];
        }
        __syncthreads();
        #pragma unroll
        for (int kk = 0; kk < BK; kk++) {
            const float4 av = *reinterpret_cast<const float4*>(&As[kk][tm << 2]);
            const float4 xv = *reinterpret_cast<const float4*>(&Xs[kk][tn << 2]);
            float a[4] = {av.x, av.y, av.z, av.w};
            float x[4] = {xv.x, xv.y, xv.z, xv.w};
            #pragma unroll
            for (int i = 0; i < 4; i++)
                #pragma unroll
                for (int j = 0; j < 4; j++)
                    acc[i][j] += a[i] * x[j];
        }
        __syncthreads();
    }

    #pragma unroll
    for (int i = 0; i < 4; i++) {
        int m = m0 + (tm << 2) + i;
        float bi = bias[m];
        float4 o;
        o.x = acc[i][0] + bi; o.y = acc[i][1] + bi;
        o.z = acc[i][2] + bi; o.w = acc[i][3] + bi;
        if (RELU) {
            o.x = fmaxf(o.x, 0.f); o.y = fmaxf(o.y, 0.f);
            o.z = fmaxf(o.z, 0.f); o.w = fmaxf(o.w, 0.f);
        }
        *reinterpret_cast<float4*>(&Cb[(long)m * N + n0 + (tn << 2)]) = o;
    }
}

// ---------------------------------------------------------------------------
// Sinkhorn: per-batch block. Fills dust-bin row of Z, runs 3 u/v iterations
// with online logsumexp, writes u[b][65], v[b][2304]. P is NOT materialized.
// ---------------------------------------------------------------------------
__global__ __launch_bounds__(1024)
void sinkhorn_uv(float* __restrict__ Z, const float* __restrict__ alpha,
                 float* __restrict__ u_out, float* __restrict__ v_out)
{
    const int b = blockIdx.x;
    float* Zb = Z + (long)b * M1 * HW_N;
    __shared__ float sv[HW_N];
    __shared__ float su[M1];
    const int tid = threadIdx.x;
    const float norm = -logf(NORM_ARG);
    const float logmu_last = logf((float)(HW_N - KK)) + norm;

    const float a = alpha[0];
    for (int j = tid; j < HW_N; j += 1024) {
        Zb[(long)KK * HW_N + j] = a;   // dust-bin row
        sv[j] = 0.f;                   // v = 0
    }
    __syncthreads();

    const int wave = tid >> 6, lane = tid & 63;

    for (int it = 0; it < 3; it++) {
        // ---- u = log_mu - LSE_n(Z + v) : one wave per row, round-robin
        for (int i = wave; i < M1; i += 16) {
            const float* zr = Zb + (long)i * HW_N;
            float m = -INFINITY, s = 0.f;
            for (int j = lane; j < HW_N; j += 64) {
                float val = zr[j] + sv[j];
                float mn = fmaxf(m, val);
                s = s * __expf(m - mn) + __expf(val - mn);
                m = mn;
            }
            #pragma unroll
            for (int off = 32; off > 0; off >>= 1) {
                float m2 = __shfl_xor(m, off);
                float s2 = __shfl_xor(s, off);
                float mn = fmaxf(m, m2);
                s = s * __expf(m - mn) + s2 * __expf(m2 - mn);
                m = mn;
            }
            if (lane == 0) {
                float logmu = (i < KK) ? norm : logmu_last;
                su[i] = logmu - (m + __logf(s));
            }
        }
        __syncthreads();
        // ---- v = log_nu - LSE_m(Z + u) : one thread per column
        for (int j = tid; j < HW_N; j += 1024) {
            float m = -INFINITY, s = 0.f;
            for (int i = 0; i < M1; i++) {
                float val = Zb[(long)i * HW_N + j] + su[i];
                float mn = fmaxf(m, val);
                s = s * __expf(m - mn) + __expf(val - mn);
                m = mn;
            }
            sv[j] = norm - (m + __logf(s));
        }
        __syncthreads();
    }

    for (int j = tid; j < HW_N; j += 1024) v_out[(long)b * HW_N + j] = sv[j];
    if (tid < M1) u_out[b * M1 + tid] = su[tid];
}

// ---------------------------------------------------------------------------
// Pooling partials: block (chunk c, batch b) computes
// part[b][c][d][k] = sum_{n in chunk} f[b][d][n] * exp(Z[b][k][n]+u+v-norm)
// 128x64 output, 256-token chunk, 16-token LDS staging, 4x8 per thread.
// ---------------------------------------------------------------------------
__global__ __launch_bounds__(256)
void agg_partial(const float* __restrict__ f, const float* __restrict__ Z,
                 const float* __restrict__ u, const float* __restrict__ v,
                 float* __restrict__ part)
{
    const int c = blockIdx.x;   // 0..8
    const int b = blockIdx.y;   // 0..31
    const int n0 = c << 8;      // 256-token chunk
    const float norm = -logf(NORM_ARG);

    __shared__ float Fs[16][132];  // [nn][d]
    __shared__ float Ps[16][68];   // [nn][k]

    const float* fb = f + (long)b * DD * HW_N;
    const float* Zb = Z + (long)b * M1 * HW_N;
    const float* ub = u + b * M1;
    const float* vb = v + (long)b * HW_N;

    const int tid = threadIdx.x;
    const int td = tid & 31;    // d-group: 4 rows each
    const int tk = tid >> 5;    // k-group: 8 cols each

    float acc[4][8] = {};

    for (int nt = 0; nt < 256; nt += 16) {
        #pragma unroll
        for (int i = 0; i < 8; i++) {          // F tile 128x16
            int li = tid + (i << 8);
            int d = li >> 4, nn = li & 15;
            Fs[nn][d] = fb[(long)d * HW_N + n0 + nt + nn];
        }
        #pragma unroll
        for (int i = 0; i < 4; i++) {          // P tile 64x16 (exp on the fly)
            int li = tid + (i << 8);
            int k = li >> 4, nn = li & 15;
            int n = n0 + nt + nn;
            Ps[nn][k] = __expf(Zb[(long)k * HW_N + n] + ub[k] + vb[n] - norm);
        }
        __syncthreads();
        #pragma unroll
        for (int nn = 0; nn < 16; nn++) {
            const float4 av = *reinterpret_cast<const float4*>(&Fs[nn][td << 2]);
            const float4 p0 = *reinterpret_cast<const float4*>(&Ps[nn][tk << 3]);
            const float4 p1 = *reinterpret_cast<const float4*>(&Ps[nn][(tk << 3) + 4]);
            float a[4] = {av.x, av.y, av.z, av.w};
            float p[8] = {p0.x, p0.y, p0.z, p0.w, p1.x, p1.y, p1.z, p1.w};
            #pragma unroll
            for (int i = 0; i < 4; i++)
                #pragma unroll
                for (int j = 0; j < 8; j++)
                    acc[i][j] += a[i] * p[j];
        }
        __syncthreads();
    }

    float* pb = part + (long)(b * 9 + c) * (DD * KK);
    #pragma unroll
    for (int i = 0; i < 4; i++) {
        int d = (td << 2) + i;
        float4 o0 = make_float4(acc[i][0], acc[i][1], acc[i][2], acc[i][3]);
        float4 o1 = make_float4(acc[i][4], acc[i][5], acc[i][6], acc[i][7]);
        *reinterpret_cast<float4*>(&pb[d * KK + (tk << 3)]) = o0;
        *reinterpret_cast<float4*>(&pb[d * KK + (tk << 3) + 4]) = o1;
    }
}

// ---------------------------------------------------------------------------
// Reduce 9 partials, L2-normalize over d per (b,k), write out[b][d*64+k].
// ---------------------------------------------------------------------------
__global__ __launch_bounds__(256)
void finalize(const float* __restrict__ part, float* __restrict__ out)
{
    const int b = blockIdx.x;
    __shared__ float agg[DD * KK];   // 32 KB
    __shared__ float nrm[KK];
    const int tid = threadIdx.x;

    for (int idx = tid; idx < DD * KK; idx += 256) {
        float s = 0.f;
        #pragma unroll
        for (int cc = 0; cc < 9; cc++)
            s += part[(long)(b * 9 + cc) * (DD * KK) + idx];
        agg[idx] = s;
    }
    __syncthreads();
    if (tid < KK) {
        float ss = 0.f;
        for (int d = 0; d < DD; d++) { float t = agg[d * KK + tid]; ss += t * t; }
        nrm[tid] = fmaxf(sqrtf(ss), 1e-12f);
    }
    __syncthreads();
    for (int idx = tid; idx < DD * KK; idx += 256)
        out[(long)b * (DD * KK) + idx] = agg[idx] / nrm[idx & 63];
}

// ---------------------------------------------------------------------------
extern "C" void kernel_launch(void* const* d_in, const int* in_sizes, int n_in,
                              void* d_out, int out_size, void* d_ws, size_t ws_size,
                              hipStream_t stream)
{
    const float* x     = (const float*)d_in[0];
    const float* w1    = (const float*)d_in[1];
    const float* b1    = (const float*)d_in[2];
    const float* w2    = (const float*)d_in[3];
    const float* b2    = (const float*)d_in[4];
    const float* s1    = (const float*)d_in[5];
    const float* c1    = (const float*)d_in[6];
    const float* s2    = (const float*)d_in[7];
    const float* c2    = (const float*)d_in[8];
    const float* alpha = (const float*)d_in[9];
    float* out = (float*)d_out;

    // workspace layout (floats); peak ~104.5 MB
    float* ws = (float*)d_ws;
    float* h    = ws;                       // 8*512*2304      = 9,437,184
    float* f    = h + 9437184;              // 32*128*2304     = 9,437,184
    float* Z    = f + 9437184;              // 32*65*2304      = 4,792,320
    float* u    = Z + 4792320;              // 32*65           = 2,080
    float* v    = u + 2080;                 // 32*2304         = 73,728
    float* part = v + 73728;                // 32*9*128*64     = 2,359,296

    // process 8 batches per slice to keep h-buffer small; h reused per branch
    for (int bs = 0; bs < BATCH; bs += 8) {
        gemm_bias_act<true ><<<dim3(36, 8, 8), 256, 0, stream>>>(
            w1, b1, x + (long)bs * CB * HW_N, (long)CB * HW_N,
            h, (long)HIDD * HW_N, HIDD, CB, HW_N);
        gemm_bias_act<false><<<dim3(36, 2, 8), 256, 0, stream>>>(
            w2, b2, h, (long)HIDD * HW_N,
            f + (long)bs * DD * HW_N, (long)DD * HW_N, DD, HIDD, HW_N);
        gemm_bias_act<true ><<<dim3(36, 8, 8), 256, 0, stream>>>(
            s1, c1, x + (long)bs * CB * HW_N, (long)CB * HW_N,
            h, (long)HIDD * HW_N, HIDD, CB, HW_N);
        gemm_bias_act<false><<<dim3(36, 1, 8), 256, 0, stream>>>(
            s2, c2, h, (long)HIDD * HW_N,
            Z + (long)bs * M1 * HW_N, (long)M1 * HW_N, KK, HIDD, HW_N);
    }

    sinkhorn_uv<<<32, 1024, 0, stream>>>(Z, alpha, u, v);
    agg_partial<<<dim3(9, 32), 256, 0, stream>>>(f, Z, u, v, part);
    finalize<<<32, 256, 0, stream>>>(part, out);
}

// Round 2
// 401.829 us; speedup vs baseline: 3.4163x; 3.4163x over previous
//
#include <hip/hip_runtime.h>
#include <math.h>
#include <stdint.h>

#define HW_N 2304      // tokens
#define CB   384
#define HIDD 512
#define DD   128
#define KK   64
#define BATCH 32
#define M1   65
#define NORM_ARG 2368.0f   // m + n

typedef __bf16 bf16;
typedef __bf16 bf16x8 __attribute__((ext_vector_type(8)));
typedef float  f32x4  __attribute__((ext_vector_type(4)));

// async global->LDS, 16 B per lane; LDS dest = wave-uniform base + lane*16
__device__ __forceinline__ void gld16(void* lds, const void* g) {
    __builtin_amdgcn_global_load_lds(
        (const __attribute__((address_space(1))) uint32_t*)g,
        (__attribute__((address_space(3))) uint32_t*)lds, 16, 0, 0);
}

// ---------------------------------------------------------------------------
// Transpose+convert: x[b][CB][HW_N] f32 -> xT[b][HW_N][CB] bf16 (token-major)
// ---------------------------------------------------------------------------
__global__ __launch_bounds__(256)
void x_to_bf16T(const float* __restrict__ x, bf16* __restrict__ xT)
{
    const int b  = blockIdx.z;
    const int n0 = blockIdx.x * 64;
    const int c0 = blockIdx.y * 64;
    __shared__ float t[64][65];
    const int tx = threadIdx.x & 15, ty = threadIdx.x >> 4;
    const float* xb = x + (long)b * CB * HW_N;
    #pragma unroll
    for (int r = 0; r < 64; r += 16) {
        const float4 vv = *(const float4*)&xb[(long)(c0 + r + ty) * HW_N + n0 + tx * 4];
        t[r + ty][tx * 4 + 0] = vv.x; t[r + ty][tx * 4 + 1] = vv.y;
        t[r + ty][tx * 4 + 2] = vv.z; t[r + ty][tx * 4 + 3] = vv.w;
    }
    __syncthreads();
    bf16* ob = xT + (long)b * HW_N * CB;
    #pragma unroll
    for (int r = 0; r < 64; r += 16) {
        const int n = r + ty;
        union { bf16 h[4]; uint2 u2; } pk;
        pk.h[0] = (bf16)t[tx * 4 + 0][n]; pk.h[1] = (bf16)t[tx * 4 + 1][n];
        pk.h[2] = (bf16)t[tx * 4 + 2][n]; pk.h[3] = (bf16)t[tx * 4 + 3][n];
        *(uint2*)&ob[(long)(n0 + n) * CB + c0 + tx * 4] = pk.u2;
    }
}

// ---------------------------------------------------------------------------
// Weight convert f32 -> bf16 (layout unchanged)
// ---------------------------------------------------------------------------
__global__ __launch_bounds__(256)
void f2bf4(const float* __restrict__ in, bf16* __restrict__ out, int n4)
{
    int i = blockIdx.x * 256 + threadIdx.x;
    if (i < n4) {
        float4 vv = ((const float4*)in)[i];
        union { bf16 h[4]; uint2 u2; } pk;
        pk.h[0] = (bf16)vv.x; pk.h[1] = (bf16)vv.y;
        pk.h[2] = (bf16)vv.z; pk.h[3] = (bf16)vv.w;
        ((uint2*)out)[i] = pk.u2;
    }
}

// ---------------------------------------------------------------------------
// MFMA GEMM, token-major: OUT[n][m] = act(sum_k XT[n][k]*W[m][k] + bias[m])
// A-frag from XT (rows=n), B-frag from W (cols=m), both k-contiguous b128.
// BM = FM*32 (n-tile), BN = FN*32 (m-tile); 4 waves in 2x2 grid.
// OUT_MODE: 0 = [b][n][Mcols] bf16 ; 1 = [b][m][Nrows] bf16 ; 2 = [b][m][Nrows] f32
// ---------------------------------------------------------------------------
template<int FM, int FN, int OUT_MODE, bool RELU>
__global__ __launch_bounds__(256)
void mfma_gemm(const bf16* __restrict__ XT, long xStride,
               const bf16* __restrict__ W,
               const float* __restrict__ bias,
               void* __restrict__ OUT, long oStride,
               int Nrows, int Mcols, int K)
{
    constexpr int BM = FM * 32;
    constexpr int BN = FN * 32;
    __shared__ __align__(16) bf16 As[BM * 32];
    __shared__ __align__(16) bf16 Bs[BN * 32];

    const int tid  = threadIdx.x;
    const int lane = tid & 63;
    const int w    = tid >> 6;
    const int wr   = w >> 1, wc = w & 1;
    const int b    = blockIdx.z;
    const int n0   = blockIdx.x * BM;
    const int m0   = blockIdx.y * BN;

    const bf16* Xb = XT + (long)b * xStride + (long)n0 * K;
    const bf16* Wb = W + (long)m0 * K;

    f32x4 acc[FM][FN];
    #pragma unroll
    for (int i = 0; i < FM; i++)
        #pragma unroll
        for (int j = 0; j < FN; j++)
            acc[i][j] = (f32x4){0.f, 0.f, 0.f, 0.f};

    const int rowq = lane >> 2;          // 0..15
    const int colb = (lane & 3) * 16;    // byte within 64B k-row

    for (int k0 = 0; k0 < K; k0 += 32) {
        #pragma unroll
        for (int t = 0; t < BM / 64; t++) {          // A tile: BM rows x 64B
            const int ii = t * 4 + w;
            gld16((char*)As + ii * 1024,
                  (const char*)(Xb + (long)(ii * 16 + rowq) * K + k0) + colb);
        }
        #pragma unroll
        for (int t = 0; t < BN / 64; t++) {          // B tile: BN rows x 64B
            const int ii = t * 4 + w;
            gld16((char*)Bs + ii * 1024,
                  (const char*)(Wb + (long)(ii * 16 + rowq) * K + k0) + colb);
        }
        __syncthreads();

        bf16x8 a[FM], bb[FN];
        #pragma unroll
        for (int i = 0; i < FM; i++)
            a[i] = *(const bf16x8*)(As + (wr * FM * 16 + i * 16 + (lane & 15)) * 32 + (lane >> 4) * 8);
        #pragma unroll
        for (int j = 0; j < FN; j++)
            bb[j] = *(const bf16x8*)(Bs + (wc * FN * 16 + j * 16 + (lane & 15)) * 32 + (lane >> 4) * 8);

        #pragma unroll
        for (int i = 0; i < FM; i++)
            #pragma unroll
            for (int j = 0; j < FN; j++)
                acc[i][j] = __builtin_amdgcn_mfma_f32_16x16x32_bf16(a[i], bb[j], acc[i][j], 0, 0, 0);
        __syncthreads();
    }

    const int fr = lane & 15;   // m within fragment (col)
    const int fq = lane >> 4;   // n row-group
    #pragma unroll
    for (int i = 0; i < FM; i++) {
        #pragma unroll
        for (int j = 0; j < FN; j++) {
            const int mg = m0 + wc * FN * 16 + j * 16 + fr;
            const float bv = bias[mg];
            #pragma unroll
            for (int r = 0; r < 4; r++) {
                const int ng = n0 + wr * FM * 16 + i * 16 + fq * 4 + r;
                float val = acc[i][j][r] + bv;
                if (RELU) val = fmaxf(val, 0.f);
                if (OUT_MODE == 0)
                    ((bf16*)OUT)[(long)b * oStride + (long)ng * Mcols + mg] = (bf16)val;
                else if (OUT_MODE == 1)
                    ((bf16*)OUT)[(long)b * oStride + (long)mg * Nrows + ng] = (bf16)val;
                else
                    ((float*)OUT)[(long)b * oStride + (long)mg * Nrows + ng] = val;
            }
        }
    }
}

// ---------------------------------------------------------------------------
// Sinkhorn passes. Z[b][64][HW_N] f32 (scores only). Dust row is analytic.
// u[b][65] (u[64] = dust), v[b][HW_N].
// ---------------------------------------------------------------------------
template<bool FIRST>
__global__ __launch_bounds__(256)
void sink_u(const float* __restrict__ Z, const float* __restrict__ v,
            const float* __restrict__ alpha, float* __restrict__ u)
{
    const int b = blockIdx.y;
    const int i = blockIdx.x * 4 + (threadIdx.x >> 6);
    if (i > KK) return;
    const int lane = threadIdx.x & 63;
    const float* zr = Z + ((long)b * KK + i) * HW_N;   // deref only when i<KK
    const float* vb = v + (long)b * HW_N;
    const float a = alpha[0];
    float m = -INFINITY, s = 0.f;
    for (int j = lane; j < HW_N; j += 64) {
        float val = (i < KK) ? zr[j] : a;
        if (!FIRST) val += vb[j];
        float mn = fmaxf(m, val);
        s = s * __expf(m - mn) + __expf(val - mn);
        m = mn;
    }
    #pragma unroll
    for (int off = 32; off; off >>= 1) {
        float m2 = __shfl_xor(m, off), s2 = __shfl_xor(s, off);
        float mn = fmaxf(m, m2);
        s = s * __expf(m - mn) + s2 * __expf(m2 - mn);
        m = mn;
    }
    if (lane == 0) {
        const float norm = -logf(NORM_ARG);
        const float logmu = (i < KK) ? norm : (logf((float)(HW_N - KK)) + norm);
        u[b * M1 + i] = logmu - (m + __logf(s));
    }
}

__global__ __launch_bounds__(64)
void sink_v(const float* __restrict__ Z, const float* __restrict__ u,
            const float* __restrict__ alpha, float* __restrict__ v)
{
    const int b = blockIdx.y;
    const int n = blockIdx.x * 64 + threadIdx.x;
    const float* ub = u + b * M1;
    const float* Zb = Z + (long)b * KK * HW_N;
    float m = alpha[0] + ub[KK];   // dust contribution
    float s = 1.f;
    for (int i = 0; i < KK; i++) {
        float t = Zb[(long)i * HW_N + n] + ub[i];
        float mn = fmaxf(m, t);
        s = s * __expf(m - mn) + __expf(t - mn);
        m = mn;
    }
    const float norm = -logf(NORM_ARG);
    v[(long)b * HW_N + n] = norm - (m + __logf(s));
}

// ---------------------------------------------------------------------------
// Pooling partials: part[b][c][d][k] = sum_{n in chunk} f[d][n]*P[k][n]
// P recomputed as exp(Z+u+v-norm). f is bf16 [b][DD][HW_N].
// ---------------------------------------------------------------------------
__global__ __launch_bounds__(256)
void agg_partial(const bf16* __restrict__ f, const float* __restrict__ Z,
                 const float* __restrict__ u, const float* __restrict__ v,
                 float* __restrict__ part)
{
    const int c = blockIdx.x;
    const int b = blockIdx.y;
    const int n0 = c << 8;
    const float norm = -logf(NORM_ARG);

    __shared__ float Fs[16][132];
    __shared__ float Ps[16][68];

    const bf16*  fb = f + (long)b * DD * HW_N;
    const float* Zb = Z + (long)b * KK * HW_N;
    const float* ub = u + b * M1;
    const float* vb = v + (long)b * HW_N;

    const int tid = threadIdx.x;
    const int td = tid & 31;
    const int tk = tid >> 5;

    float acc[4][8] = {};

    for (int nt = 0; nt < 256; nt += 16) {
        #pragma unroll
        for (int i = 0; i < 8; i++) {
            int li = tid + (i << 8);
            int d = li >> 4, nn = li & 15;
            Fs[nn][d] = (float)fb[(long)d * HW_N + n0 + nt + nn];
        }
        #pragma unroll
        for (int i = 0; i < 4; i++) {
            int li = tid + (i << 8);
            int k = li >> 4, nn = li & 15;
            int n = n0 + nt + nn;
            Ps[nn][k] = __expf(Zb[(long)k * HW_N + n] + ub[k] + vb[n] - norm);
        }
        __syncthreads();
        #pragma unroll
        for (int nn = 0; nn < 16; nn++) {
            const float4 av = *reinterpret_cast<const float4*>(&Fs[nn][td << 2]);
            const float4 p0 = *reinterpret_cast<const float4*>(&Ps[nn][tk << 3]);
            const float4 p1 = *reinterpret_cast<const float4*>(&Ps[nn][(tk << 3) + 4]);
            float a[4] = {av.x, av.y, av.z, av.w};
            float p[8] = {p0.x, p0.y, p0.z, p0.w, p1.x, p1.y, p1.z, p1.w};
            #pragma unroll
            for (int i = 0; i < 4; i++)
                #pragma unroll
                for (int j = 0; j < 8; j++)
                    acc[i][j] += a[i] * p[j];
        }
        __syncthreads();
    }

    float* pb = part + (long)(b * 9 + c) * (DD * KK);
    #pragma unroll
    for (int i = 0; i < 4; i++) {
        int d = (td << 2) + i;
        float4 o0 = make_float4(acc[i][0], acc[i][1], acc[i][2], acc[i][3]);
        float4 o1 = make_float4(acc[i][4], acc[i][5], acc[i][6], acc[i][7]);
        *reinterpret_cast<float4*>(&pb[d * KK + (tk << 3)]) = o0;
        *reinterpret_cast<float4*>(&pb[d * KK + (tk << 3) + 4]) = o1;
    }
}

__global__ __launch_bounds__(256)
void finalize(const float* __restrict__ part, float* __restrict__ out)
{
    const int b = blockIdx.x;
    __shared__ float agg[DD * KK];
    __shared__ float nrm[KK];
    const int tid = threadIdx.x;

    for (int idx = tid; idx < DD * KK; idx += 256) {
        float s = 0.f;
        #pragma unroll
        for (int cc = 0; cc < 9; cc++)
            s += part[(long)(b * 9 + cc) * (DD * KK) + idx];
        agg[idx] = s;
    }
    __syncthreads();
    if (tid < KK) {
        float ss = 0.f;
        for (int d = 0; d < DD; d++) { float t = agg[d * KK + tid]; ss += t * t; }
        nrm[tid] = fmaxf(sqrtf(ss), 1e-12f);
    }
    __syncthreads();
    for (int idx = tid; idx < DD * KK; idx += 256)
        out[(long)b * (DD * KK) + idx] = agg[idx] / nrm[idx & 63];
}

// ---------------------------------------------------------------------------
extern "C" void kernel_launch(void* const* d_in, const int* in_sizes, int n_in,
                              void* d_out, int out_size, void* d_ws, size_t ws_size,
                              hipStream_t stream)
{
    const float* x     = (const float*)d_in[0];
    const float* w1    = (const float*)d_in[1];
    const float* b1    = (const float*)d_in[2];
    const float* w2    = (const float*)d_in[3];
    const float* b2    = (const float*)d_in[4];
    const float* s1    = (const float*)d_in[5];
    const float* c1    = (const float*)d_in[6];
    const float* s2    = (const float*)d_in[7];
    const float* c2    = (const float*)d_in[8];
    const float* alpha = (const float*)d_in[9];
    float* out = (float*)d_out;

    // workspace layout (bytes), all 16B-aligned; total ~81.5 MB
    char* p = (char*)d_ws;
    bf16* w1b = (bf16*)p;  p += (long)HIDD * CB * 2;
    bf16* w2b = (bf16*)p;  p += (long)DD * HIDD * 2;
    bf16* s1b = (bf16*)p;  p += (long)HIDD * CB * 2;
    bf16* s2b = (bf16*)p;  p += (long)KK * HIDD * 2;
    bf16* xTs = (bf16*)p;  p += (long)8 * HW_N * CB * 2;
    bf16* hs  = (bf16*)p;  p += (long)8 * HW_N * HIDD * 2;
    bf16* f   = (bf16*)p;  p += (long)BATCH * DD * HW_N * 2;
    float* Z  = (float*)p; p += (long)BATCH * KK * HW_N * 4;
    float* u  = (float*)p; p += (long)BATCH * M1 * 4;        // 8320, stays 16B-aligned
    float* v  = (float*)p; p += (long)BATCH * HW_N * 4;
    float* part = (float*)p;

    f2bf4<<<(HIDD * CB / 4 + 255) / 256, 256, 0, stream>>>(w1, w1b, HIDD * CB / 4);
    f2bf4<<<(DD * HIDD / 4 + 255) / 256, 256, 0, stream>>>(w2, w2b, DD * HIDD / 4);
    f2bf4<<<(HIDD * CB / 4 + 255) / 256, 256, 0, stream>>>(s1, s1b, HIDD * CB / 4);
    f2bf4<<<(KK * HIDD / 4 + 255) / 256, 256, 0, stream>>>(s2, s2b, KK * HIDD / 4);

    for (int bs = 0; bs < BATCH; bs += 8) {
        x_to_bf16T<<<dim3(36, 6, 8), 256, 0, stream>>>(x + (long)bs * CB * HW_N, xTs);
        // h = relu(xT @ w1^T + b1)  -> token-major bf16
        mfma_gemm<4, 4, 0, true><<<dim3(18, 4, 8), 256, 0, stream>>>(
            xTs, (long)HW_N * CB, w1b, b1, hs, (long)HW_N * HIDD, HW_N, HIDD, CB);
        // f = h @ w2^T + b2 -> chan-major bf16 [b][DD][HW_N]
        mfma_gemm<2, 4, 1, false><<<dim3(36, 1, 8), 256, 0, stream>>>(
            hs, (long)HW_N * HIDD, w2b, b2, f + (long)bs * DD * HW_N,
            (long)DD * HW_N, HW_N, DD, HIDD);
        // hs = relu(xT @ s1^T + c1)
        mfma_gemm<4, 4, 0, true><<<dim3(18, 4, 8), 256, 0, stream>>>(
            xTs, (long)HW_N * CB, s1b, c1, hs, (long)HW_N * HIDD, HW_N, HIDD, CB);
        // Z = hs @ s2^T + c2 -> chan-major f32 [b][KK][HW_N]
        mfma_gemm<2, 2, 2, false><<<dim3(36, 1, 8), 256, 0, stream>>>(
            hs, (long)HW_N * HIDD, s2b, c2, Z + (long)bs * KK * HW_N,
            (long)KK * HW_N, HW_N, KK, HIDD);
    }

    sink_u<true ><<<dim3(17, 32), 256, 0, stream>>>(Z, v, alpha, u);
    sink_v<<<dim3(36, 32), 64, 0, stream>>>(Z, u, alpha, v);
    sink_u<false><<<dim3(17, 32), 256, 0, stream>>>(Z, v, alpha, u);
    sink_v<<<dim3(36, 32), 64, 0, stream>>>(Z, u, alpha, v);
    sink_u<false><<<dim3(17, 32), 256, 0, stream>>>(Z, v, alpha, u);
    sink_v<<<dim3(36, 32), 64, 0, stream>>>(Z, u, alpha, v);

    agg_partial<<<dim3(9, 32), 256, 0, stream>>>(f, Z, u, v, part);
    finalize<<<32, 256, 0, stream>>>(part, out);
}

// Round 3
// 313.215 us; speedup vs baseline: 4.3829x; 1.2829x over previous
//
#include <hip/hip_runtime.h>
#include <math.h>
#include <stdint.h>

#define HW_N 2304
#define CB   384
#define HIDD 512
#define HID2 1024      // fused w1||s1
#define DD   128
#define KK   64
#define BATCH 32
#define M1   65
#define NTOK (BATCH * HW_N)   // 73728 flattened tokens
#define NORM_ARG 2368.0f

typedef __bf16 bf16;
typedef __bf16 bf16x8 __attribute__((ext_vector_type(8)));
typedef float  f32x4  __attribute__((ext_vector_type(4)));

__device__ __forceinline__ void gld16(void* lds, const void* g) {
    __builtin_amdgcn_global_load_lds(
        (const __attribute__((address_space(1))) uint32_t*)g,
        (__attribute__((address_space(3))) uint32_t*)lds, 16, 0, 0);
}

// ---------------------------------------------------------------------------
// x[b][CB][HW_N] f32 -> xT[b][HW_N][CB] bf16, all batches
// ---------------------------------------------------------------------------
__global__ __launch_bounds__(256)
void x_to_bf16T(const float* __restrict__ x, bf16* __restrict__ xT)
{
    const int b  = blockIdx.z;
    const int n0 = blockIdx.x * 64;
    const int c0 = blockIdx.y * 64;
    __shared__ float t[64][65];
    const int tx = threadIdx.x & 15, ty = threadIdx.x >> 4;
    const float* xb = x + (long)b * CB * HW_N;
    #pragma unroll
    for (int r = 0; r < 64; r += 16) {
        const float4 vv = *(const float4*)&xb[(long)(c0 + r + ty) * HW_N + n0 + tx * 4];
        t[r + ty][tx * 4 + 0] = vv.x; t[r + ty][tx * 4 + 1] = vv.y;
        t[r + ty][tx * 4 + 2] = vv.z; t[r + ty][tx * 4 + 3] = vv.w;
    }
    __syncthreads();
    bf16* ob = xT + (long)b * HW_N * CB;
    #pragma unroll
    for (int r = 0; r < 64; r += 16) {
        const int n = r + ty;
        union { bf16 h[4]; uint2 u2; } pk;
        pk.h[0] = (bf16)t[tx * 4 + 0][n]; pk.h[1] = (bf16)t[tx * 4 + 1][n];
        pk.h[2] = (bf16)t[tx * 4 + 2][n]; pk.h[3] = (bf16)t[tx * 4 + 3][n];
        *(uint2*)&ob[(long)(n0 + n) * CB + c0 + tx * 4] = pk.u2;
    }
}

__global__ __launch_bounds__(256)
void f2bf4(const float* __restrict__ in, bf16* __restrict__ out, int n4)
{
    int i = blockIdx.x * 256 + threadIdx.x;
    if (i < n4) {
        float4 vv = ((const float4*)in)[i];
        union { bf16 h[4]; uint2 u2; } pk;
        pk.h[0] = (bf16)vv.x; pk.h[1] = (bf16)vv.y;
        pk.h[2] = (bf16)vv.z; pk.h[3] = (bf16)vv.w;
        ((uint2*)out)[i] = pk.u2;
    }
}

__global__ __launch_bounds__(256)
void concat_bias(const float* __restrict__ b1, const float* __restrict__ c1,
                 float* __restrict__ bc)
{
    int i = blockIdx.x * 256 + threadIdx.x;
    if (i < HIDD) bc[i] = b1[i];
    else if (i < HID2) bc[i] = c1[i - HIDD];
}

// ---------------------------------------------------------------------------
// Generic MFMA GEMM over k-major operands:
//   OUT(ra, rb) = act( A[ra][:K] . B[rb][:K] + bias )
// MFMA D-layout: lane fq=lane>>4, fr=lane&15 holds D[ra = fq*4+r][rb = fr].
// Tile: BA = FA*32 a-rows, BB = FB*32 b-rows; 4 waves (2x2).
// OUT_MODE 0: OUT[rb][ra] bf16, row stride ldo (bias on ra, packed along ra)
// OUT_MODE 1: ra = global token -> (b, n); OUT[((b*ldo)+rb)*HW_N + n] bf16
// OUT_MODE 2: same addressing, f32 (bias on rb for modes 1/2)
// ---------------------------------------------------------------------------
template<int FA, int FB, int OUT_MODE, bool RELU, bool SWIZZLE>
__global__ __launch_bounds__(256)
void mfma_gemm(const bf16* __restrict__ A, int lda,
               const bf16* __restrict__ B, int ldb,
               const float* __restrict__ bias,
               void* __restrict__ OUT, int ldo,
               int K, int nA)
{
    constexpr int BA = FA * 32;
    constexpr int BB = FB * 32;
    __shared__ __align__(16) bf16 As[BA * 32];
    __shared__ __align__(16) bf16 Bs[BB * 32];

    int L = blockIdx.x;
    if (SWIZZLE) { const int cpx = gridDim.x >> 3; L = (L & 7) * cpx + (L >> 3); }
    const int ta = L % nA;
    const int tb = L / nA;

    const int tid  = threadIdx.x;
    const int lane = tid & 63;
    const int w    = tid >> 6;
    const int wr   = w >> 1, wc = w & 1;

    const bf16* Ap = A + (long)ta * BA * lda;
    const bf16* Bp = B + (long)tb * BB * ldb;

    f32x4 acc[FA][FB];
    #pragma unroll
    for (int i = 0; i < FA; i++)
        #pragma unroll
        for (int j = 0; j < FB; j++)
            acc[i][j] = (f32x4){0.f, 0.f, 0.f, 0.f};

    const int rowq = lane >> 2;
    const int colb = (lane & 3) * 16;

    for (int k0 = 0; k0 < K; k0 += 32) {
        #pragma unroll
        for (int t = 0; t < BA / 64; t++) {
            const int ii = t * 4 + w;
            gld16((char*)As + ii * 1024,
                  (const char*)(Ap + (long)(ii * 16 + rowq) * lda + k0) + colb);
        }
        #pragma unroll
        for (int t = 0; t < BB / 64; t++) {
            const int ii = t * 4 + w;
            gld16((char*)Bs + ii * 1024,
                  (const char*)(Bp + (long)(ii * 16 + rowq) * ldb + k0) + colb);
        }
        __syncthreads();

        bf16x8 a[FA], bb[FB];
        #pragma unroll
        for (int i = 0; i < FA; i++)
            a[i] = *(const bf16x8*)(As + (wr * FA * 16 + i * 16 + (lane & 15)) * 32 + (lane >> 4) * 8);
        #pragma unroll
        for (int j = 0; j < FB; j++)
            bb[j] = *(const bf16x8*)(Bs + (wc * FB * 16 + j * 16 + (lane & 15)) * 32 + (lane >> 4) * 8);

        #pragma unroll
        for (int i = 0; i < FA; i++)
            #pragma unroll
            for (int j = 0; j < FB; j++)
                acc[i][j] = __builtin_amdgcn_mfma_f32_16x16x32_bf16(a[i], bb[j], acc[i][j], 0, 0, 0);
        __syncthreads();
    }

    const int fr = lane & 15;
    const int fq = lane >> 4;

    if (OUT_MODE == 0) {
        #pragma unroll
        for (int i = 0; i < FA; i++) {
            const int ra0 = ta * BA + wr * FA * 16 + i * 16 + fq * 4;
            const float4 bv = *(const float4*)&bias[ra0];
            #pragma unroll
            for (int j = 0; j < FB; j++) {
                const int rb = tb * BB + wc * FB * 16 + j * 16 + fr;
                union { bf16 h[4]; uint2 u2; } pk;
                float v0 = acc[i][j][0] + bv.x, v1 = acc[i][j][1] + bv.y;
                float v2 = acc[i][j][2] + bv.z, v3 = acc[i][j][3] + bv.w;
                if (RELU) {
                    v0 = fmaxf(v0, 0.f); v1 = fmaxf(v1, 0.f);
                    v2 = fmaxf(v2, 0.f); v3 = fmaxf(v3, 0.f);
                }
                pk.h[0] = (bf16)v0; pk.h[1] = (bf16)v1;
                pk.h[2] = (bf16)v2; pk.h[3] = (bf16)v3;
                *(uint2*)&((bf16*)OUT)[(long)rb * ldo + ra0] = pk.u2;
            }
        }
    } else {
        #pragma unroll
        for (int i = 0; i < FA; i++) {
            const int g0 = ta * BA + wr * FA * 16 + i * 16 + fq * 4;
            const int bi = g0 / HW_N;
            const int nn = g0 - bi * HW_N;
            #pragma unroll
            for (int j = 0; j < FB; j++) {
                const int mg = tb * BB + wc * FB * 16 + j * 16 + fr;
                const float bvs = bias[mg];
                float v0 = acc[i][j][0] + bvs, v1 = acc[i][j][1] + bvs;
                float v2 = acc[i][j][2] + bvs, v3 = acc[i][j][3] + bvs;
                if (RELU) {
                    v0 = fmaxf(v0, 0.f); v1 = fmaxf(v1, 0.f);
                    v2 = fmaxf(v2, 0.f); v3 = fmaxf(v3, 0.f);
                }
                const long base = ((long)bi * ldo + mg) * HW_N + nn;
                if (OUT_MODE == 1) {
                    union { bf16 h[4]; uint2 u2; } pk;
                    pk.h[0] = (bf16)v0; pk.h[1] = (bf16)v1;
                    pk.h[2] = (bf16)v2; pk.h[3] = (bf16)v3;
                    *(uint2*)&((bf16*)OUT)[base] = pk.u2;
                } else {
                    *(float4*)&((float*)OUT)[base] = make_float4(v0, v1, v2, v3);
                }
            }
        }
    }
}

// ---------------------------------------------------------------------------
// Sinkhorn passes (dust row analytic). Z[b][64][HW_N] f32.
// ---------------------------------------------------------------------------
template<bool FIRST>
__global__ __launch_bounds__(256)
void sink_u(const float* __restrict__ Z, const float* __restrict__ v,
            const float* __restrict__ alpha, float* __restrict__ u)
{
    const int b = blockIdx.y;
    const int i = blockIdx.x * 4 + (threadIdx.x >> 6);
    if (i > KK) return;
    const int lane = threadIdx.x & 63;
    const float* zr = Z + ((long)b * KK + i) * HW_N;
    const float* vb = v + (long)b * HW_N;
    const float a = alpha[0];
    float m = -INFINITY, s = 0.f;
    for (int j = lane; j < HW_N; j += 64) {
        float val = (i < KK) ? zr[j] : a;
        if (!FIRST) val += vb[j];
        float mn = fmaxf(m, val);
        s = s * __expf(m - mn) + __expf(val - mn);
        m = mn;
    }
    #pragma unroll
    for (int off = 32; off; off >>= 1) {
        float m2 = __shfl_xor(m, off), s2 = __shfl_xor(s, off);
        float mn = fmaxf(m, m2);
        s = s * __expf(m - mn) + s2 * __expf(m2 - mn);
        m = mn;
    }
    if (lane == 0) {
        const float norm = -logf(NORM_ARG);
        const float logmu = (i < KK) ? norm : (logf((float)(HW_N - KK)) + norm);
        u[b * M1 + i] = logmu - (m + __logf(s));
    }
}

__global__ __launch_bounds__(64)
void sink_v(const float* __restrict__ Z, const float* __restrict__ u,
            const float* __restrict__ alpha, float* __restrict__ v)
{
    const int b = blockIdx.y;
    const int n = blockIdx.x * 64 + threadIdx.x;
    const float* ub = u + b * M1;
    const float* Zb = Z + (long)b * KK * HW_N;
    float m = alpha[0] + ub[KK];
    float s = 1.f;
    for (int i = 0; i < KK; i++) {
        float t = Zb[(long)i * HW_N + n] + ub[i];
        float mn = fmaxf(m, t);
        s = s * __expf(m - mn) + __expf(t - mn);
        m = mn;
    }
    const float norm = -logf(NORM_ARG);
    v[(long)b * HW_N + n] = norm - (m + __logf(s));
}

// ---------------------------------------------------------------------------
// Pooling partials + finalize (unchanged from round 2)
// ---------------------------------------------------------------------------
__global__ __launch_bounds__(256)
void agg_partial(const bf16* __restrict__ f, const float* __restrict__ Z,
                 const float* __restrict__ u, const float* __restrict__ v,
                 float* __restrict__ part)
{
    const int c = blockIdx.x;
    const int b = blockIdx.y;
    const int n0 = c << 8;
    const float norm = -logf(NORM_ARG);

    __shared__ float Fs[16][132];
    __shared__ float Ps[16][68];

    const bf16*  fb = f + (long)b * DD * HW_N;
    const float* Zb = Z + (long)b * KK * HW_N;
    const float* ub = u + b * M1;
    const float* vb = v + (long)b * HW_N;

    const int tid = threadIdx.x;
    const int td = tid & 31;
    const int tk = tid >> 5;

    float acc[4][8] = {};

    for (int nt = 0; nt < 256; nt += 16) {
        #pragma unroll
        for (int i = 0; i < 8; i++) {
            int li = tid + (i << 8);
            int d = li >> 4, nn = li & 15;
            Fs[nn][d] = (float)fb[(long)d * HW_N + n0 + nt + nn];
        }
        #pragma unroll
        for (int i = 0; i < 4; i++) {
            int li = tid + (i << 8);
            int k = li >> 4, nn = li & 15;
            int n = n0 + nt + nn;
            Ps[nn][k] = __expf(Zb[(long)k * HW_N + n] + ub[k] + vb[n] - norm);
        }
        __syncthreads();
        #pragma unroll
        for (int nn = 0; nn < 16; nn++) {
            const float4 av = *reinterpret_cast<const float4*>(&Fs[nn][td << 2]);
            const float4 p0 = *reinterpret_cast<const float4*>(&Ps[nn][tk << 3]);
            const float4 p1 = *reinterpret_cast<const float4*>(&Ps[nn][(tk << 3) + 4]);
            float a[4] = {av.x, av.y, av.z, av.w};
            float p[8] = {p0.x, p0.y, p0.z, p0.w, p1.x, p1.y, p1.z, p1.w};
            #pragma unroll
            for (int i = 0; i < 4; i++)
                #pragma unroll
                for (int j = 0; j < 8; j++)
                    acc[i][j] += a[i] * p[j];
        }
        __syncthreads();
    }

    float* pb = part + (long)(b * 9 + c) * (DD * KK);
    #pragma unroll
    for (int i = 0; i < 4; i++) {
        int d = (td << 2) + i;
        float4 o0 = make_float4(acc[i][0], acc[i][1], acc[i][2], acc[i][3]);
        float4 o1 = make_float4(acc[i][4], acc[i][5], acc[i][6], acc[i][7]);
        *reinterpret_cast<float4*>(&pb[d * KK + (tk << 3)]) = o0;
        *reinterpret_cast<float4*>(&pb[d * KK + (tk << 3) + 4]) = o1;
    }
}

__global__ __launch_bounds__(256)
void finalize(const float* __restrict__ part, float* __restrict__ out)
{
    const int b = blockIdx.x;
    __shared__ float agg[DD * KK];
    __shared__ float nrm[KK];
    const int tid = threadIdx.x;

    for (int idx = tid; idx < DD * KK; idx += 256) {
        float s = 0.f;
        #pragma unroll
        for (int cc = 0; cc < 9; cc++)
            s += part[(long)(b * 9 + cc) * (DD * KK) + idx];
        agg[idx] = s;
    }
    __syncthreads();
    if (tid < KK) {
        float ss = 0.f;
        for (int d = 0; d < DD; d++) { float t = agg[d * KK + tid]; ss += t * t; }
        nrm[tid] = fmaxf(sqrtf(ss), 1e-12f);
    }
    __syncthreads();
    for (int idx = tid; idx < DD * KK; idx += 256)
        out[(long)b * (DD * KK) + idx] = agg[idx] / nrm[idx & 63];
}

// ---------------------------------------------------------------------------
extern "C" void kernel_launch(void* const* d_in, const int* in_sizes, int n_in,
                              void* d_out, int out_size, void* d_ws, size_t ws_size,
                              hipStream_t stream)
{
    const float* x     = (const float*)d_in[0];
    const float* w1    = (const float*)d_in[1];
    const float* b1    = (const float*)d_in[2];
    const float* w2    = (const float*)d_in[3];
    const float* b2    = (const float*)d_in[4];
    const float* s1    = (const float*)d_in[5];
    const float* c1    = (const float*)d_in[6];
    const float* s2    = (const float*)d_in[7];
    const float* c2    = (const float*)d_in[8];
    const float* alpha = (const float*)d_in[9];
    float* out = (float*)d_out;

    // workspace layout; total ~256 MB
    char* p = (char*)d_ws;
    bf16* Wc  = (bf16*)p;  p += (long)HID2 * CB * 2;       // w1 rows then s1 rows
    bf16* w2b = (bf16*)p;  p += (long)DD * HIDD * 2;
    bf16* s2b = (bf16*)p;  p += (long)KK * HIDD * 2;
    float* bc = (float*)p; p += (long)HID2 * 4;            // b1 || c1
    bf16* xT  = (bf16*)p;  p += (long)NTOK * CB * 2;       // 56.6 MB
    bf16* hs  = (bf16*)p;  p += (long)NTOK * HID2 * 2;     // 151 MB
    bf16* f   = (bf16*)p;  p += (long)BATCH * DD * HW_N * 2;
    float* Z  = (float*)p; p += (long)BATCH * KK * HW_N * 4;
    float* u  = (float*)p; p += (long)BATCH * M1 * 4;
    float* v  = (float*)p; p += (long)BATCH * HW_N * 4;
    float* part = (float*)p;

    // weight/bias conversion
    f2bf4<<<(HIDD * CB / 4 + 255) / 256, 256, 0, stream>>>(w1, Wc, HIDD * CB / 4);
    f2bf4<<<(HIDD * CB / 4 + 255) / 256, 256, 0, stream>>>(s1, Wc + (long)HIDD * CB, HIDD * CB / 4);
    f2bf4<<<(DD * HIDD / 4 + 255) / 256, 256, 0, stream>>>(w2, w2b, DD * HIDD / 4);
    f2bf4<<<(KK * HIDD / 4 + 255) / 256, 256, 0, stream>>>(s2, s2b, KK * HIDD / 4);
    concat_bias<<<4, 256, 0, stream>>>(b1, c1, bc);

    // x -> token-major bf16, all batches
    x_to_bf16T<<<dim3(36, 6, 32), 256, 0, stream>>>(x, xT);

    // stage 1 (fused w1||s1): hs[g][1024] = relu(xT @ Wc^T + bc)
    // A = Wc (m, packed stores along m), B = xT (tokens); XCD-chunked swizzle
    mfma_gemm<4, 4, 0, true, true><<<(HID2 / 128) * (NTOK / 128), 256, 0, stream>>>(
        Wc, CB, xT, CB, bc, hs, HID2, CB, HID2 / 128);

    // stage 2a: f[b][d][n] = hs[:, 0:512] @ w2^T + b2   (bf16, packed along n)
    mfma_gemm<4, 4, 1, false, false><<<NTOK / 128, 256, 0, stream>>>(
        hs, HID2, w2b, HIDD, b2, f, DD, HIDD, NTOK / 128);

    // stage 2b: Z[b][k][n] = hs[:, 512:1024] @ s2^T + c2  (f32, packed along n)
    mfma_gemm<4, 2, 2, false, false><<<NTOK / 128, 256, 0, stream>>>(
        hs + HIDD, HID2, s2b, HIDD, c2, Z, KK, HIDD, NTOK / 128);

    // Sinkhorn (3 iterations)
    sink_u<true ><<<dim3(17, 32), 256, 0, stream>>>(Z, v, alpha, u);
    sink_v<<<dim3(36, 32), 64, 0, stream>>>(Z, u, alpha, v);
    sink_u<false><<<dim3(17, 32), 256, 0, stream>>>(Z, v, alpha, u);
    sink_v<<<dim3(36, 32), 64, 0, stream>>>(Z, u, alpha, v);
    sink_u<false><<<dim3(17, 32), 256, 0, stream>>>(Z, v, alpha, u);
    sink_v<<<dim3(36, 32), 64, 0, stream>>>(Z, u, alpha, v);

    agg_partial<<<dim3(9, 32), 256, 0, stream>>>(f, Z, u, v, part);
    finalize<<<32, 256, 0, stream>>>(part, out);
}